// Round 13
// baseline (1676.171 us; speedup 1.0000x reference)
//
#include <hip/hip_runtime.h>
#include <hip/hip_bf16.h>
#include <hip/hip_cooperative_groups.h>

namespace cg = cooperative_groups;

#define NSP   20000
#define NSPAT 10000
#define ESS   160000
#define EBIP  320000
#define ESP   320000

static inline int cdiv_host(long a, long b) { return (int)((a + b - 1) / b); }

__device__ __forceinline__ float wave_red_sum(float p) {
#pragma unroll
  for (int m = 32; m >= 1; m >>= 1) p += __shfl_xor(p, m, 64);
  return p;
}
__device__ __forceinline__ float bf2f(unsigned short u) {
  return __uint_as_float(((unsigned int)u) << 16);
}
__device__ __forceinline__ unsigned short f2bf(float f) {
  unsigned int u = __float_as_uint(f);
  unsigned int r = (u + 0x7FFF + ((u >> 16) & 1)) >> 16;  // RN-even
  return (unsigned short)r;
}

struct XSrc { const float* p[5]; int w[5]; int n; };
struct P64 {
  XSrc xs; int M, K;
  const float* W; const float* bias; int mode;  // 0 plain, 1 relu, 2 split
  const float* a_s; const float* a_d;
  float* al_s; float* al_d;
  float* Y; float* Y2;
};
struct P256 {
  XSrc xs; int M, K;
  const float* W;
  const float* a_s; const float* a_d;
  float* al_s; float* al_d;
  unsigned short* Y;   // bf16 out
};

struct MegaArgs {
  // zero region
  uint4* zbase; int zwords;
  // CSR inputs
  const int *ss_row, *ss_col; const float* ss_eaI;
  const int *bp_row, *bp_col; const float* bp_eaI;
  const int *pp_row, *pp_col; const float* pp_eaI;
  int *ss_cp, *bp_cp, *pp_cp;
  int *ss_rnk, *bp_rnk, *pp_rnk;
  int *ss_cnt, *bp_cnt, *pp_cnt;
  int *ss_ptr, *bp_ptr, *pp_ptr;
  int *ss_src; float* ss_cea;
  int *bp_src; float* bp_cea;
  int *pp_src; float* pp_cea;
  float *ss_lea, *pp_lea;
  const unsigned int* mask; int* flag;
  // misc
  const float* We[5]; const float* ae[5]; float* dotes;
  const float* mean; const float* stdv; const float* sx; const float* sgd;
  float* spc96; float* h0;
  // projections
  P64 sl, bpWd, bpWs, fc;
  P256 sg0, sg1, pg0, pg1;
  // gat
  float *alS, *alD, *alSb, *alDb;
  const unsigned short* HS;
  const float *sg0_b, *sg1_b, *pg0_b, *pg1_b, *bp_b;
  float *h_a, *h_b, *sts, *x1;
};

// ---------------------------------------------------------------------------
// phase bodies (all grid-stride, NO early returns on the mega path)
// ---------------------------------------------------------------------------
__device__ void proj64_tile(const P64& J, int bid, float* wl, float* xl) {
  constexpr int KC = 32, BR = 32, KCP = 36;
  int t = threadIdx.x;
  long row0 = (long)bid * BR;
  int cg_ = t & 15, rg = t >> 4;
  int c0 = cg_ * 4;
  float acc[2][4];
#pragma unroll
  for (int r = 0; r < 2; ++r)
#pragma unroll
    for (int j = 0; j < 4; ++j) acc[r][j] = 0.f;

  for (int k0 = 0; k0 < J.K; k0 += KC) {
    int seg = 0, base = 0;
    while (k0 >= base + J.xs.w[seg]) { base += J.xs.w[seg]; ++seg; }
    const float* Xp = J.xs.p[seg];
    int stride = J.xs.w[seg];
    int kloc = k0 - base;
    __syncthreads();
    {
      const float4* ws = (const float4*)(J.W + (long)k0 * 64);
      float4* wd = (float4*)wl;
      wd[t] = ws[t];
      wd[t + 256] = ws[t + 256];
    }
    {
      int r = t >> 3, kq = (t & 7) * 4;
      long rr = row0 + r; if (rr >= J.M) rr = J.M - 1;
      float4 v = *(const float4*)(Xp + rr * stride + kloc + kq);
      *(float4*)(xl + r * KCP + kq) = v;
    }
    __syncthreads();
    for (int kg = 0; kg < KC; kg += 4) {
      float4 w0 = *(const float4*)(wl + (kg + 0) * 64 + c0);
      float4 w1 = *(const float4*)(wl + (kg + 1) * 64 + c0);
      float4 w2 = *(const float4*)(wl + (kg + 2) * 64 + c0);
      float4 w3 = *(const float4*)(wl + (kg + 3) * 64 + c0);
#pragma unroll
      for (int r = 0; r < 2; ++r) {
        float4 xv = *(const float4*)(xl + (rg * 2 + r) * KCP + kg);
        acc[r][0] = fmaf(xv.x, w0.x, acc[r][0]);
        acc[r][1] = fmaf(xv.x, w0.y, acc[r][1]);
        acc[r][2] = fmaf(xv.x, w0.z, acc[r][2]);
        acc[r][3] = fmaf(xv.x, w0.w, acc[r][3]);
        acc[r][0] = fmaf(xv.y, w1.x, acc[r][0]);
        acc[r][1] = fmaf(xv.y, w1.y, acc[r][1]);
        acc[r][2] = fmaf(xv.y, w1.z, acc[r][2]);
        acc[r][3] = fmaf(xv.y, w1.w, acc[r][3]);
        acc[r][0] = fmaf(xv.z, w2.x, acc[r][0]);
        acc[r][1] = fmaf(xv.z, w2.y, acc[r][1]);
        acc[r][2] = fmaf(xv.z, w2.z, acc[r][2]);
        acc[r][3] = fmaf(xv.z, w2.w, acc[r][3]);
        acc[r][0] = fmaf(xv.w, w3.x, acc[r][0]);
        acc[r][1] = fmaf(xv.w, w3.y, acc[r][1]);
        acc[r][2] = fmaf(xv.w, w3.z, acc[r][2]);
        acc[r][3] = fmaf(xv.w, w3.w, acc[r][3]);
      }
    }
  }

  float4 bv = make_float4(0.f, 0.f, 0.f, 0.f);
  float4 asv = make_float4(0.f, 0.f, 0.f, 0.f);
  float4 adv = make_float4(0.f, 0.f, 0.f, 0.f);
  if (J.bias) bv = *(const float4*)(J.bias + c0);
  if (J.a_s) asv = *(const float4*)(J.a_s + c0);
  if (J.a_d) adv = *(const float4*)(J.a_d + c0);

#pragma unroll
  for (int r = 0; r < 2; ++r) {
    long m = row0 + rg * 2 + r;
    bool ok = m < J.M;
    float v0 = acc[r][0] + bv.x, v1 = acc[r][1] + bv.y;
    float v2 = acc[r][2] + bv.z, v3 = acc[r][3] + bv.w;
    if (J.mode == 1) {
      if (ok)
        *(float4*)(J.Y + m * 64 + c0) = make_float4(
            fmaxf(v0, 0.f), fmaxf(v1, 0.f), fmaxf(v2, 0.f), fmaxf(v3, 0.f));
    } else if (J.mode == 2) {
      if (ok) {
        if (c0 < 32) {
          *(float4*)(J.Y + m * 32 + c0) = make_float4(v0, v1, v2, v3);
        } else {
          float4 o;
          o.x = fmaxf(v0, 0.f) + log1pf(__expf(-fabsf(v0))) + 1e-6f;
          o.y = fmaxf(v1, 0.f) + log1pf(__expf(-fabsf(v1))) + 1e-6f;
          o.z = fmaxf(v2, 0.f) + log1pf(__expf(-fabsf(v2))) + 1e-6f;
          o.w = fmaxf(v3, 0.f) + log1pf(__expf(-fabsf(v3))) + 1e-6f;
          *(float4*)(J.Y2 + m * 32 + (c0 - 32)) = o;
        }
      }
    } else if (ok && J.Y) {
      *(float4*)(J.Y + m * 64 + c0) = make_float4(v0, v1, v2, v3);
    }
    if (J.a_s) {
      float s = acc[r][0] * asv.x + acc[r][1] * asv.y + acc[r][2] * asv.z + acc[r][3] * asv.w;
      s += __shfl_xor(s, 1); s += __shfl_xor(s, 2);
      s += __shfl_xor(s, 4); s += __shfl_xor(s, 8);
      if (ok && cg_ == 0) J.al_s[m] = s;
    }
    if (J.a_d) {
      float s = acc[r][0] * adv.x + acc[r][1] * adv.y + acc[r][2] * adv.z + acc[r][3] * adv.w;
      s += __shfl_xor(s, 1); s += __shfl_xor(s, 2);
      s += __shfl_xor(s, 4); s += __shfl_xor(s, 8);
      if (ok && cg_ == 0) J.al_d[m] = s;
    }
  }
}

__device__ void proj64_grid(const P64& J, float* wl, float* xl) {
  int nb = (J.M + 31) >> 5;
  for (int b = blockIdx.x; b < nb; b += gridDim.x) proj64_tile(J, b, wl, xl);
}

__device__ void proj256_grid(const P256& J, float* wl, float* xl) {
  constexpr int KC = 32, RPT = 8, BR = 32, KCP = 36;
  int t = threadIdx.x;
  int cg_ = t & 63, rg = t >> 6;
  int c0 = cg_ * 4;
  int nb = (J.M + 31) >> 5;
  for (int b = blockIdx.x; b < nb; b += gridDim.x) {
    long row0 = (long)b * BR;
    float acc[RPT][4];
#pragma unroll
    for (int r = 0; r < RPT; ++r)
#pragma unroll
      for (int j = 0; j < 4; ++j) acc[r][j] = 0.f;

    for (int k0 = 0; k0 < J.K; k0 += KC) {
      int kc = min(KC, J.K - k0);
      int seg = 0, base = 0;
      while (k0 >= base + J.xs.w[seg]) { base += J.xs.w[seg]; ++seg; }
      const float* Xp = J.xs.p[seg];
      int stride = J.xs.w[seg];
      int kloc = k0 - base;
      __syncthreads();
      {
        const float4* wsrc = (const float4*)(J.W + (long)k0 * 256);
        float4* wdst = (float4*)wl;
        for (int i = t; i < (kc * 256) >> 2; i += 256) wdst[i] = wsrc[i];
      }
      for (int i = t; i < BR * 8; i += 256) {
        int r = i >> 3, kq = (i & 7) * 4;
        if (kq < kc) {
          long rr = row0 + r; if (rr >= J.M) rr = J.M - 1;
          float4 v = *(const float4*)(Xp + rr * stride + kloc + kq);
          *(float4*)(xl + r * KCP + kq) = v;
        }
      }
      __syncthreads();
      for (int kg = 0; kg < kc; kg += 4) {
        float4 w0 = *(const float4*)(wl + (kg + 0) * 256 + c0);
        float4 w1 = *(const float4*)(wl + (kg + 1) * 256 + c0);
        float4 w2 = *(const float4*)(wl + (kg + 2) * 256 + c0);
        float4 w3 = *(const float4*)(wl + (kg + 3) * 256 + c0);
        float4 xv[RPT];
#pragma unroll
        for (int r = 0; r < RPT; ++r)
          xv[r] = *(const float4*)(xl + (rg * RPT + r) * KCP + kg);
#pragma unroll
        for (int r = 0; r < RPT; ++r) {
          acc[r][0] = fmaf(xv[r].x, w0.x, acc[r][0]);
          acc[r][1] = fmaf(xv[r].x, w0.y, acc[r][1]);
          acc[r][2] = fmaf(xv[r].x, w0.z, acc[r][2]);
          acc[r][3] = fmaf(xv[r].x, w0.w, acc[r][3]);
          acc[r][0] = fmaf(xv[r].y, w1.x, acc[r][0]);
          acc[r][1] = fmaf(xv[r].y, w1.y, acc[r][1]);
          acc[r][2] = fmaf(xv[r].y, w1.z, acc[r][2]);
          acc[r][3] = fmaf(xv[r].y, w1.w, acc[r][3]);
          acc[r][0] = fmaf(xv[r].z, w2.x, acc[r][0]);
          acc[r][1] = fmaf(xv[r].z, w2.y, acc[r][1]);
          acc[r][2] = fmaf(xv[r].z, w2.z, acc[r][2]);
          acc[r][3] = fmaf(xv[r].z, w2.w, acc[r][3]);
          acc[r][0] = fmaf(xv[r].w, w3.x, acc[r][0]);
          acc[r][1] = fmaf(xv[r].w, w3.y, acc[r][1]);
          acc[r][2] = fmaf(xv[r].w, w3.z, acc[r][2]);
          acc[r][3] = fmaf(xv[r].w, w3.w, acc[r][3]);
        }
      }
    }

    float4 asv = *(const float4*)(J.a_s + c0);
    float4 adv = *(const float4*)(J.a_d + c0);
#pragma unroll
    for (int r = 0; r < RPT; ++r) {
      long m = row0 + (long)rg * RPT + r;
      bool ok = m < J.M;
      if (ok) {
        ushort4 o;
        o.x = f2bf(acc[r][0]); o.y = f2bf(acc[r][1]);
        o.z = f2bf(acc[r][2]); o.w = f2bf(acc[r][3]);
        *(ushort4*)(J.Y + m * 256 + c0) = o;
      }
      float s = acc[r][0] * asv.x + acc[r][1] * asv.y + acc[r][2] * asv.z + acc[r][3] * asv.w;
      s += __shfl_xor(s, 1); s += __shfl_xor(s, 2);
      s += __shfl_xor(s, 4); s += __shfl_xor(s, 8);
      if (ok && (cg_ & 15) == 0) J.al_s[m * 4 + (c0 >> 6)] = s;
      float d = acc[r][0] * adv.x + acc[r][1] * adv.y + acc[r][2] * adv.z + acc[r][3] * adv.w;
      d += __shfl_xor(d, 1); d += __shfl_xor(d, 2);
      d += __shfl_xor(d, 4); d += __shfl_xor(d, 8);
      if (ok && (cg_ & 15) == 0) J.al_d[m * 4 + (c0 >> 6)] = d;
    }
  }
}

__device__ __forceinline__ void fma4_bf(float4& a, float al, ushort4 u) {
  a.x = fmaf(al, bf2f(u.x), a.x); a.y = fmaf(al, bf2f(u.y), a.y);
  a.z = fmaf(al, bf2f(u.z), a.z); a.w = fmaf(al, bf2f(u.w), a.w);
}
__device__ __forceinline__ void scale4(float4& a, float s) {
  a.x *= s; a.y *= s; a.z *= s; a.w *= s;
}

__device__ void gat4_grid(int Nd, const int* dptr, const int* csr_src,
                          const float* csr_ea, const float* al_s, const float* al_d,
                          const float* dote, const float* loop_ea,
                          const unsigned short* hs, const float* bias, float* out) {
  int wave = threadIdx.x >> 6, lane = threadIdx.x & 63;
  int h = lane >> 4;
  float de = dote[h];
  for (int n = blockIdx.x * 4 + wave; n < Nd; n += gridDim.x * 4) {
    float ald = al_d[(long)n * 4 + h];
    int e0 = dptr[n], e1 = dptr[n + 1];
    float l = al_s[(long)n * 4 + h] + ald + loop_ea[n] * de;
    l = (l > 0.f) ? l : 0.2f * l;
    float m0 = l, d0 = 1.f;
    float4 a0;
    {
      ushort4 u = *(const ushort4*)(hs + (long)n * 256 + lane * 4);
      a0.x = bf2f(u.x); a0.y = bf2f(u.y); a0.z = bf2f(u.z); a0.w = bf2f(u.w);
    }
    float m1 = -INFINITY, d1 = 0.f;
    float4 a1 = make_float4(0.f, 0.f, 0.f, 0.f);
    int e = e0;
    for (; e + 2 <= e1; e += 2) {
      int s0 = csr_src[e], s1 = csr_src[e + 1];
      float l0 = al_s[(long)s0 * 4 + h] + ald + csr_ea[e] * de;
      float l1 = al_s[(long)s1 * 4 + h] + ald + csr_ea[e + 1] * de;
      l0 = (l0 > 0.f) ? l0 : 0.2f * l0;
      l1 = (l1 > 0.f) ? l1 : 0.2f * l1;
      ushort4 u0 = *(const ushort4*)(hs + (long)s0 * 256 + lane * 4);
      ushort4 u1 = *(const ushort4*)(hs + (long)s1 * 256 + lane * 4);
      if (l0 > m0) { float sc = __expf(m0 - l0); d0 *= sc; scale4(a0, sc); m0 = l0; }
      float ex0 = __expf(l0 - m0);
      d0 += ex0;
      fma4_bf(a0, ex0, u0);
      if (l1 > m1) { float sc = __expf(m1 - l1); d1 *= sc; scale4(a1, sc); m1 = l1; }
      float ex1 = __expf(l1 - m1);
      d1 += ex1;
      fma4_bf(a1, ex1, u1);
    }
    if (e < e1) {
      int s0 = csr_src[e];
      float l0 = al_s[(long)s0 * 4 + h] + ald + csr_ea[e] * de;
      l0 = (l0 > 0.f) ? l0 : 0.2f * l0;
      ushort4 u0 = *(const ushort4*)(hs + (long)s0 * 256 + lane * 4);
      if (l0 > m0) { float sc = __expf(m0 - l0); d0 *= sc; scale4(a0, sc); m0 = l0; }
      float ex0 = __expf(l0 - m0);
      d0 += ex0;
      fma4_bf(a0, ex0, u0);
    }
    if (m1 != -INFINITY) {
      float M = fmaxf(m0, m1);
      float sA = __expf(m0 - M);
      float sB = __expf(m1 - M);
      d0 = d0 * sA + d1 * sB;
      a0.x = a0.x * sA + a1.x * sB; a0.y = a0.y * sA + a1.y * sB;
      a0.z = a0.z * sA + a1.z * sB; a0.w = a0.w * sA + a1.w * sB;
    }
    float inv = 1.f / (d0 + 1e-16f);
    scale4(a0, inv);
    a0.x += __shfl_xor(a0.x, 16); a0.y += __shfl_xor(a0.y, 16);
    a0.z += __shfl_xor(a0.z, 16); a0.w += __shfl_xor(a0.w, 16);
    a0.x += __shfl_xor(a0.x, 32); a0.y += __shfl_xor(a0.y, 32);
    a0.z += __shfl_xor(a0.z, 32); a0.w += __shfl_xor(a0.w, 32);
    if (lane < 16) {
      float4 b = *(const float4*)(bias + lane * 4);
      float4 o;
      o.x = fmaxf(a0.x * 0.25f + b.x, 0.f);
      o.y = fmaxf(a0.y * 0.25f + b.y, 0.f);
      o.z = fmaxf(a0.z * 0.25f + b.z, 0.f);
      o.w = fmaxf(a0.w * 0.25f + b.w, 0.f);
      *(float4*)(out + (long)n * 64 + lane * 4) = o;
    }
  }
}

__device__ void gat1_grid(int Nd, const int* dptr, const int* csr_src,
                          const float* csr_ea, const float* al_s, const float* al_d,
                          const float* dote, const float* hs, const float* bias,
                          float* out) {
  int wave = threadIdx.x >> 6, lane = threadIdx.x & 63;
  float de = dote[0];
  for (int n = blockIdx.x * 4 + wave; n < Nd; n += gridDim.x * 4) {
    float ald = al_d[n];
    int e0 = dptr[n], e1 = dptr[n + 1];
    float m0 = -INFINITY, d0 = 0.f, acc0 = 0.f;
    float m1 = -INFINITY, d1 = 0.f, acc1 = 0.f;
    int e = e0;
    for (; e + 2 <= e1; e += 2) {
      int s0 = csr_src[e], s1 = csr_src[e + 1];
      float l0 = al_s[s0] + ald + csr_ea[e] * de;
      float l1 = al_s[s1] + ald + csr_ea[e + 1] * de;
      l0 = (l0 > 0.f) ? l0 : 0.2f * l0;
      l1 = (l1 > 0.f) ? l1 : 0.2f * l1;
      float h0 = hs[(long)s0 * 64 + lane];
      float h1 = hs[(long)s1 * 64 + lane];
      if (l0 > m0) { float sc = __expf(m0 - l0); d0 *= sc; acc0 *= sc; m0 = l0; }
      float ex0 = __expf(l0 - m0);
      d0 += ex0; acc0 = fmaf(ex0, h0, acc0);
      if (l1 > m1) { float sc = __expf(m1 - l1); d1 *= sc; acc1 *= sc; m1 = l1; }
      float ex1 = __expf(l1 - m1);
      d1 += ex1; acc1 = fmaf(ex1, h1, acc1);
    }
    if (e < e1) {
      int s0 = csr_src[e];
      float l0 = al_s[s0] + ald + csr_ea[e] * de;
      l0 = (l0 > 0.f) ? l0 : 0.2f * l0;
      float h0 = hs[(long)s0 * 64 + lane];
      if (l0 > m0) { float sc = __expf(m0 - l0); d0 *= sc; acc0 *= sc; m0 = l0; }
      float ex0 = __expf(l0 - m0);
      d0 += ex0; acc0 = fmaf(ex0, h0, acc0);
    }
    if (m1 != -INFINITY) {
      float M = fmaxf(m0, m1);
      float sA = (m0 == -INFINITY) ? 0.f : __expf(m0 - M);
      float sB = __expf(m1 - M);
      d0 = d0 * sA + d1 * sB;
      acc0 = acc0 * sA + acc1 * sB;
    }
    float o = acc0 / (d0 + 1e-16f);
    out[(long)n * 64 + lane] = fmaxf(o + bias[lane], 0.f);
  }
}

// ---------------------------------------------------------------------------
// THE mega kernel: whole pipeline, 17 grid syncs.
// ---------------------------------------------------------------------------
__global__ __launch_bounds__(256, 4) void mega_kernel(MegaArgs A) {
  __shared__ __align__(16) float smem[32 * 256 + 32 * 36];
  float* wl = smem;
  float* xl = smem + 32 * 256;
  cg::grid_group g = cg::this_grid();
  int t = threadIdx.x;
  int gtid = blockIdx.x * 256 + t;
  int gsz = gridDim.x * 256;

  // P0: zero partitioned counters
  for (int i = gtid; i < A.zwords; i += gsz) A.zbase[i] = make_uint4(0, 0, 0, 0);
  g.sync();

  // P1: count + mask detect
  {
    const int NB = (ESS + EBIP + ESP + 255) / 256;  // 3125
    for (int b = blockIdx.x; b < NB + 1; b += gridDim.x) {
      if (b == NB) {
        if (t < 64) {
          unsigned int w0 = A.mask[t], w1 = A.mask[t + 64];
          unsigned int w2 = A.mask[t + 128], w3 = A.mask[t + 192];
          bool ai = (w0 <= 1u) && (w1 <= 1u) && (w2 <= 1u) && (w3 <= 1u);
          bool af = (w0 == 0u || w0 == 0x3f800000u) && (w1 == 0u || w1 == 0x3f800000u) &&
                    (w2 == 0u || w2 == 0x3f800000u) && (w3 == 0u || w3 == 0x3f800000u);
          unsigned long long bi = __ballot(ai), bf = __ballot(af);
          if (t == 0) *A.flag = (bi == ~0ull) ? 0 : ((bf == ~0ull) ? 2 : 1);
        }
      } else {
        int i = b * 256 + t;
        if (i < ESS + EBIP + ESP) {
          int p = (i >> 8) & 7;
          if (i < ESS) {
            int d = A.ss_col[i]; A.ss_rnk[i] = atomicAdd(&A.ss_cp[p * NSPAT + d], 1);
          } else if (i < ESS + EBIP) {
            int j = i - ESS;
            int d = A.bp_col[j]; A.bp_rnk[j] = atomicAdd(&A.bp_cp[p * NSP + d], 1);
          } else {
            int j = i - ESS - EBIP;
            int d = A.pp_col[j]; A.pp_rnk[j] = atomicAdd(&A.pp_cp[p * NSP + d], 1);
          }
        }
      }
    }
  }
  g.sync();

  // P2: merge partitions (per-node)
  for (int i = gtid; i < NSPAT + NSP + NSP; i += gsz) {
    int *cp, *c; int n, d;
    if (i < NSPAT) { cp = A.ss_cp; c = A.ss_cnt; n = NSPAT; d = i; }
    else if (i < NSPAT + NSP) { cp = A.bp_cp; c = A.bp_cnt; n = NSP; d = i - NSPAT; }
    else { cp = A.pp_cp; c = A.pp_cnt; n = NSP; d = i - NSPAT - NSP; }
    int s = 0;
#pragma unroll
    for (int p = 0; p < 8; ++p) { int v = cp[p * n + d]; cp[p * n + d] = s; s += v; }
    c[d] = s;
  }
  g.sync();

  // P3: scan (blocks 0..2, 256 threads each)
  if (blockIdx.x < 3) {
    const int* cnt; int n; int* ptr;
    if (blockIdx.x == 0) { cnt = A.ss_cnt; n = NSPAT; ptr = A.ss_ptr; }
    else if (blockIdx.x == 1) { cnt = A.bp_cnt; n = NSP; ptr = A.bp_ptr; }
    else { cnt = A.pp_cnt; n = NSP; ptr = A.pp_ptr; }
    int* part = (int*)smem;
    int ch = (n + 255) / 256;
    int beg = t * ch, end = min(beg + ch, n);
    int s = 0;
    for (int i = beg; i < end; ++i) s += cnt[i];
    part[t] = s;
    __syncthreads();
    for (int off2 = 1; off2 < 256; off2 <<= 1) {
      int v = (t >= off2) ? part[t - off2] : 0;
      __syncthreads();
      part[t] += v;
      __syncthreads();
    }
    int run = (t == 0) ? 0 : part[t - 1];
    for (int i = beg; i < end; ++i) { ptr[i] = run; run += cnt[i]; }
    if (t == 255) ptr[n] = part[255];
  }
  g.sync();

  // P4: scatter
  for (int i = gtid; i < ESS + EBIP + ESP; i += gsz) {
    int p = (i >> 8) & 7;
    if (i < ESS) {
      int d = A.ss_col[i];
      int pos = A.ss_ptr[d] + A.ss_cp[p * NSPAT + d] + A.ss_rnk[i];
      A.ss_src[pos] = A.ss_row[i]; A.ss_cea[pos] = A.ss_eaI[i];
    } else if (i < ESS + EBIP) {
      int j = i - ESS;
      int d = A.bp_col[j];
      int pos = A.bp_ptr[d] + A.bp_cp[p * NSP + d] + A.bp_rnk[j];
      A.bp_src[pos] = A.bp_row[j]; A.bp_cea[pos] = A.bp_eaI[j];
    } else {
      int j = i - ESS - EBIP;
      int d = A.pp_col[j];
      int pos = A.pp_ptr[d] + A.pp_cp[p * NSP + d] + A.pp_rnk[j];
      A.pp_src[pos] = A.pp_row[j]; A.pp_cea[pos] = A.pp_eaI[j];
    }
  }
  g.sync();

  // P5: misc (leafin + dote + spc96/h0 prep)
  {
    const int NB_LEAF = (NSPAT + NSP + 255) / 256;           // 118
    const long totA = (long)NSP * 96, totB = (long)NSPAT * 16;
    const int NB_PREP = (int)((totA + totB + 255) / 256);    // 8125
    const int NBT = NB_LEAF + 5 + NB_PREP;
    int mode = *A.flag;
    for (int b = blockIdx.x; b < NBT; b += gridDim.x) {
      if (b < NB_LEAF) {
        int i = b * 256 + t;
        if (i < NSPAT + NSP) {
          const int* ptr; const float* cea; float* lea; int d;
          if (i < NSPAT) { ptr = A.ss_ptr; cea = A.ss_cea; lea = A.ss_lea; d = i; }
          else { ptr = A.pp_ptr; cea = A.pp_cea; lea = A.pp_lea; d = i - NSPAT; }
          int e0 = ptr[d], e1 = ptr[d + 1];
          float s = 0.f;
          for (int e = e0; e < e1; ++e) s += cea[e];
          lea[d] = s / (float)max(e1 - e0, 1);
        }
      } else if (b < NB_LEAF + 5) {
        int lb = b - NB_LEAF;
        int n = (lb == 2) ? 64 : 256;
        int off2 = lb * 4;
        if (t < n) {
          float p = wave_red_sum(A.We[lb][t] * A.ae[lb][t]);
          if ((t & 63) == 0) A.dotes[off2 + (t >> 6)] = p;
        }
      } else {
        long i = (long)(b - NB_LEAF - 5) * 256 + t;
        if (i < totA + totB) {
          if (i < totA) {
            int n = (int)(i / 96), c = (int)(i % 96);
            float v;
            if (c < 32) v = A.mean[(long)n * 32 + c];
            else if (c < 64) v = A.stdv[(long)n * 32 + (c - 32)];
            else {
              long j = (long)n * 32 + (c - 64);
              int mv;
              if (mode == 0) mv = ((const int*)A.mask)[j];
              else if (mode == 2) mv = (((const float*)A.mask)[j] != 0.0f);
              else mv = (int)((const unsigned char*)A.mask)[j];
              v = mv ? 0.f : 1.f;
            }
            A.spc96[i] = v;
          } else {
            long k = i - totA;
            int n = (int)(k / 16), c = (int)(k % 16);
            A.h0[k] = (c < 12) ? A.sx[(long)n * 12 + c] : A.sgd[(long)n * 4 + (c - 12)];
          }
        }
      }
    }
  }
  g.sync();

  // P6: sl + bpWd projections
  proj64_grid(A.sl, wl, xl);
  proj64_grid(A.bpWd, wl, xl);
  g.sync();

  // P7..P17: GNN chain
  proj256_grid(A.sg0, wl, xl);
  g.sync();
  gat4_grid(NSPAT, A.ss_ptr, A.ss_src, A.ss_cea, A.alS, A.alD, A.dotes + 0, A.ss_lea,
            A.HS, A.sg0_b, A.h_a);
  g.sync();
  proj256_grid(A.sg1, wl, xl);
  g.sync();
  gat4_grid(NSPAT, A.ss_ptr, A.ss_src, A.ss_cea, A.alS, A.alD, A.dotes + 4, A.ss_lea,
            A.HS, A.sg1_b, A.h_b);
  g.sync();
  proj64_grid(A.bpWs, wl, xl);
  g.sync();
  gat1_grid(NSP, A.bp_ptr, A.bp_src, A.bp_cea, A.alSb, A.alDb, A.dotes + 8,
            A.h_a, A.bp_b, A.sts);
  g.sync();
  proj256_grid(A.pg0, wl, xl);
  g.sync();
  gat4_grid(NSP, A.pp_ptr, A.pp_src, A.pp_cea, A.alS, A.alD, A.dotes + 12, A.pp_lea,
            A.HS, A.pg0_b, A.x1);
  g.sync();
  proj256_grid(A.pg1, wl, xl);
  g.sync();
  gat4_grid(NSP, A.pp_ptr, A.pp_src, A.pp_cea, A.alS, A.alD, A.dotes + 16, A.pp_lea,
            A.HS, A.pg1_b, A.sts);
  g.sync();
  proj64_grid(A.fc, wl, xl);
}

// ---------------------------------------------------------------------------
extern "C" void kernel_launch(void* const* d_in, const int* in_sizes, int n_in,
                              void* d_out, int out_size, void* d_ws, size_t ws_size,
                              hipStream_t stream) {
  const float* sp_mean = (const float*)d_in[0];
  const float* sp_std  = (const float*)d_in[1];
  const void*  nanmask = d_in[2];
  const float* sp_gen  = (const float*)d_in[3];
  const float* sp_phy  = (const float*)d_in[4];
  const float* spat_x  = (const float*)d_in[5];
  const float* spat_g  = (const float*)d_in[6];
  const int*   ss_ei   = (const int*)d_in[7];
  const float* ss_ea   = (const float*)d_in[8];
  const int*   bip_ei  = (const int*)d_in[9];
  const float* bip_ea  = (const float*)d_in[10];
  const int*   sp_ei   = (const int*)d_in[11];
  const float* sp_ea   = (const float*)d_in[12];
  const float* sg0_W = (const float*)d_in[13]; const float* sg0_as = (const float*)d_in[14];
  const float* sg0_ad = (const float*)d_in[15]; const float* sg0_ae = (const float*)d_in[16];
  const float* sg0_We = (const float*)d_in[17]; const float* sg0_b = (const float*)d_in[18];
  const float* sg1_W = (const float*)d_in[19]; const float* sg1_as = (const float*)d_in[20];
  const float* sg1_ad = (const float*)d_in[21]; const float* sg1_ae = (const float*)d_in[22];
  const float* sg1_We = (const float*)d_in[23]; const float* sg1_b = (const float*)d_in[24];
  const float* pg0_W = (const float*)d_in[25]; const float* pg0_as = (const float*)d_in[26];
  const float* pg0_ad = (const float*)d_in[27]; const float* pg0_ae = (const float*)d_in[28];
  const float* pg0_We = (const float*)d_in[29]; const float* pg0_b = (const float*)d_in[30];
  const float* pg1_W = (const float*)d_in[31]; const float* pg1_as = (const float*)d_in[32];
  const float* pg1_ad = (const float*)d_in[33]; const float* pg1_ae = (const float*)d_in[34];
  const float* pg1_We = (const float*)d_in[35]; const float* pg1_b = (const float*)d_in[36];
  const float* bp_Ws = (const float*)d_in[37]; const float* bp_Wd = (const float*)d_in[38];
  const float* bp_as = (const float*)d_in[39]; const float* bp_ad = (const float*)d_in[40];
  const float* bp_ae = (const float*)d_in[41]; const float* bp_We = (const float*)d_in[42];
  const float* bp_b  = (const float*)d_in[43];
  const float* sl_W  = (const float*)d_in[44]; const float* sl_b  = (const float*)d_in[45];
  const float* fc_W  = (const float*)d_in[46]; const float* fc_b  = (const float*)d_in[47];

  // ---- workspace layout ----
  char* wsb = (char*)d_ws;
  size_t off = 0;
  auto A = [&](size_t nbytes) -> void* {
    void* p = wsb + off;
    off += (nbytes + 255) & ~(size_t)255;
    return p;
  };
  int* ss_cp = (int*)A((size_t)8 * NSPAT * 4);
  int* bp_cp = (int*)A((size_t)8 * NSP * 4);
  int* pp_cp = (int*)A((size_t)8 * NSP * 4);
  size_t zbytes = off;
  int*   ss_cnt = (int*)A((NSPAT + 1) * 4);
  int*   bp_cnt = (int*)A((NSP + 1) * 4);
  int*   pp_cnt = (int*)A((NSP + 1) * 4);
  int*   flag  = (int*)A(4);
  float* dotes = (float*)A(5 * 4 * sizeof(float));
  float* alS   = (float*)A((size_t)NSP * 4 * 4);
  float* alD   = (float*)A((size_t)NSP * 4 * 4);
  float* alSb  = (float*)A((size_t)NSPAT * 4);
  float* alDb  = (float*)A((size_t)NSP * 4);
  float* spc96 = (float*)A((size_t)NSP * 96 * 4);
  float* sp_in = (float*)A((size_t)NSP * 64 * 4);
  float* h0    = (float*)A((size_t)NSPAT * 16 * 4);
  float* h_a   = (float*)A((size_t)NSPAT * 64 * 4);
  float* h_b   = (float*)A((size_t)NSPAT * 64 * 4);
  float* HS    = (float*)A((size_t)NSP * 256 * 4);
  float* sts   = (float*)A((size_t)NSP * 64 * 4);
  float* x1    = (float*)A((size_t)NSP * 64 * 4);
  int*   ss_ptr = (int*)A((NSPAT + 1) * 4);
  int*   ss_src = (int*)A((size_t)ESS * 4);
  float* ss_cea = (float*)A((size_t)ESS * 4);
  int*   ss_rnk = (int*)A((size_t)ESS * 4);
  float* ss_lea = (float*)A((size_t)NSPAT * 4);
  int*   bp_ptr = (int*)A((NSP + 1) * 4);
  int*   bp_src = (int*)A((size_t)EBIP * 4);
  float* bp_cea = (float*)A((size_t)EBIP * 4);
  int*   bp_rnk = (int*)A((size_t)EBIP * 4);
  int*   pp_ptr = (int*)A((NSP + 1) * 4);
  int*   pp_src = (int*)A((size_t)ESP * 4);
  float* pp_cea = (float*)A((size_t)ESP * 4);
  int*   pp_rnk = (int*)A((size_t)ESP * 4);
  float* pp_lea = (float*)A((size_t)NSP * 4);
  (void)ws_size; (void)in_sizes; (void)n_in; (void)out_size;

  MegaArgs ma{};
  ma.zbase = (uint4*)wsb; ma.zwords = (int)(zbytes / 16);
  ma.ss_row = ss_ei; ma.ss_col = ss_ei + ESS; ma.ss_eaI = ss_ea;
  ma.bp_row = bip_ei; ma.bp_col = bip_ei + EBIP; ma.bp_eaI = bip_ea;
  ma.pp_row = sp_ei; ma.pp_col = sp_ei + ESP; ma.pp_eaI = sp_ea;
  ma.ss_cp = ss_cp; ma.bp_cp = bp_cp; ma.pp_cp = pp_cp;
  ma.ss_rnk = ss_rnk; ma.bp_rnk = bp_rnk; ma.pp_rnk = pp_rnk;
  ma.ss_cnt = ss_cnt; ma.bp_cnt = bp_cnt; ma.pp_cnt = pp_cnt;
  ma.ss_ptr = ss_ptr; ma.bp_ptr = bp_ptr; ma.pp_ptr = pp_ptr;
  ma.ss_src = ss_src; ma.ss_cea = ss_cea;
  ma.bp_src = bp_src; ma.bp_cea = bp_cea;
  ma.pp_src = pp_src; ma.pp_cea = pp_cea;
  ma.ss_lea = ss_lea; ma.pp_lea = pp_lea;
  ma.mask = (const unsigned int*)nanmask; ma.flag = flag;
  ma.We[0] = sg0_We; ma.ae[0] = sg0_ae;
  ma.We[1] = sg1_We; ma.ae[1] = sg1_ae;
  ma.We[2] = bp_We;  ma.ae[2] = bp_ae;
  ma.We[3] = pg0_We; ma.ae[3] = pg0_ae;
  ma.We[4] = pg1_We; ma.ae[4] = pg1_ae;
  ma.dotes = dotes;
  ma.mean = sp_mean; ma.stdv = sp_std; ma.sx = spat_x; ma.sgd = spat_g;
  ma.spc96 = spc96; ma.h0 = h0;

  ma.sl.xs.p[0] = spc96; ma.sl.xs.w[0] = 96;
  ma.sl.xs.p[1] = sp_gen; ma.sl.xs.w[1] = 64;
  ma.sl.xs.p[2] = sp_phy; ma.sl.xs.w[2] = 128; ma.sl.xs.n = 3;
  ma.sl.M = NSP; ma.sl.K = 288; ma.sl.W = sl_W; ma.sl.bias = sl_b;
  ma.sl.mode = 1; ma.sl.Y = sp_in;

  ma.bpWd.xs.p[0] = sp_gen; ma.bpWd.xs.w[0] = 64;
  ma.bpWd.xs.p[1] = sp_phy; ma.bpWd.xs.w[1] = 128; ma.bpWd.xs.n = 2;
  ma.bpWd.M = NSP; ma.bpWd.K = 192; ma.bpWd.W = bp_Wd; ma.bpWd.mode = 0;
  ma.bpWd.a_d = bp_ad; ma.bpWd.al_d = alDb;

  ma.bpWs.xs.p[0] = h_b; ma.bpWs.xs.w[0] = 64; ma.bpWs.xs.n = 1;
  ma.bpWs.M = NSPAT; ma.bpWs.K = 64; ma.bpWs.W = bp_Ws; ma.bpWs.mode = 0;
  ma.bpWs.a_s = bp_as; ma.bpWs.al_s = alSb; ma.bpWs.Y = h_a;

  ma.fc.xs.p[0] = sts; ma.fc.xs.w[0] = 64; ma.fc.xs.n = 1;
  ma.fc.M = NSP; ma.fc.K = 64; ma.fc.W = fc_W; ma.fc.bias = fc_b; ma.fc.mode = 2;
  ma.fc.Y = (float*)d_out; ma.fc.Y2 = (float*)d_out + (long)NSP * 32;

  ma.sg0.xs.p[0] = h0; ma.sg0.xs.w[0] = 16; ma.sg0.xs.n = 1;
  ma.sg0.M = NSPAT; ma.sg0.K = 16; ma.sg0.W = sg0_W;
  ma.sg0.a_s = sg0_as; ma.sg0.a_d = sg0_ad; ma.sg0.al_s = alS; ma.sg0.al_d = alD;
  ma.sg0.Y = (unsigned short*)HS;

  ma.sg1.xs.p[0] = h_a; ma.sg1.xs.w[0] = 64; ma.sg1.xs.n = 1;
  ma.sg1.M = NSPAT; ma.sg1.K = 64; ma.sg1.W = sg1_W;
  ma.sg1.a_s = sg1_as; ma.sg1.a_d = sg1_ad; ma.sg1.al_s = alS; ma.sg1.al_d = alD;
  ma.sg1.Y = (unsigned short*)HS;

  ma.pg0.xs.p[0] = sts; ma.pg0.xs.w[0] = 64;
  ma.pg0.xs.p[1] = sp_in; ma.pg0.xs.w[1] = 64; ma.pg0.xs.n = 2;
  ma.pg0.M = NSP; ma.pg0.K = 128; ma.pg0.W = pg0_W;
  ma.pg0.a_s = pg0_as; ma.pg0.a_d = pg0_ad; ma.pg0.al_s = alS; ma.pg0.al_d = alD;
  ma.pg0.Y = (unsigned short*)HS;

  ma.pg1.xs.p[0] = x1; ma.pg1.xs.w[0] = 64; ma.pg1.xs.n = 1;
  ma.pg1.M = NSP; ma.pg1.K = 64; ma.pg1.W = pg1_W;
  ma.pg1.a_s = pg1_as; ma.pg1.a_d = pg1_ad; ma.pg1.al_s = alS; ma.pg1.al_d = alD;
  ma.pg1.Y = (unsigned short*)HS;

  ma.alS = alS; ma.alD = alD; ma.alSb = alSb; ma.alDb = alDb;
  ma.HS = (const unsigned short*)HS;
  ma.sg0_b = sg0_b; ma.sg1_b = sg1_b; ma.pg0_b = pg0_b; ma.pg1_b = pg1_b; ma.bp_b = bp_b;
  ma.h_a = h_a; ma.h_b = h_b; ma.sts = sts; ma.x1 = x1;

  // cooperative launch sized to co-residency
  int dev = 0;
  hipGetDevice(&dev);
  int numCU = 256;
  hipDeviceGetAttribute(&numCU, hipDeviceAttributeMultiprocessorCount, dev);
  int maxBpc = 0;
  hipOccupancyMaxActiveBlocksPerMultiprocessor(&maxBpc, (const void*)mega_kernel, 256, 0);
  if (maxBpc < 1) maxBpc = 1;
  long grid = (long)maxBpc * numCU;
  if (grid > 5000) grid = 5000;
  if (grid < 3) grid = 3;

  void* params[] = { &ma };
  hipLaunchCooperativeKernel((const void*)mega_kernel, dim3((unsigned)grid), dim3(256),
                             params, 0, stream);
}

// Round 14
// 496.978 us; speedup vs baseline: 3.3727x; 3.3727x over previous
//
#include <hip/hip_runtime.h>
#include <hip/hip_bf16.h>

#define NSP   20000
#define NSPAT 10000
#define ESS   160000
#define EBIP  320000
#define ESP   320000

static inline int cdiv_host(long a, long b) { return (int)((a + b - 1) / b); }

__device__ __forceinline__ float wave_red_sum(float p) {
#pragma unroll
  for (int m = 32; m >= 1; m >>= 1) p += __shfl_xor(p, m, 64);
  return p;
}
__device__ __forceinline__ float bf2f(unsigned short u) {
  return __uint_as_float(((unsigned int)u) << 16);
}
__device__ __forceinline__ unsigned short f2bf(float f) {
  unsigned int u = __float_as_uint(f);
  unsigned int r = (u + 0x7FFF + ((u >> 16) & 1)) >> 16;  // RN-even
  return (unsigned short)r;
}

// ---------------------------------------------------------------------------
// CSR count, 8-way partitioned atomics + mask-format detect (last block).
// ---------------------------------------------------------------------------
__global__ void count3_kernel(
    const int* c1, int E1, int* cp1, int* rnk1, int n1,
    const int* c2, int E2, int* cp2, int* rnk2, int n2,
    const int* c3, int E3, int* cp3, int* rnk3, int n3,
    const unsigned int* __restrict__ mask, int* __restrict__ flag) {
  int b = blockIdx.x, t = threadIdx.x;
  if (b == gridDim.x - 1) {
    if (t < 64) {
      unsigned int w0 = mask[t], w1 = mask[t + 64], w2 = mask[t + 128], w3 = mask[t + 192];
      bool ai = (w0 <= 1u) && (w1 <= 1u) && (w2 <= 1u) && (w3 <= 1u);
      auto okf = [](unsigned int w) { return w == 0u || w == 0x3f800000u; };
      bool af = okf(w0) && okf(w1) && okf(w2) && okf(w3);
      unsigned long long bi = __ballot(ai), bf = __ballot(af);
      if (t == 0) *flag = (bi == ~0ull) ? 0 : ((bf == ~0ull) ? 2 : 1);
    }
    return;
  }
  int i = b * 256 + t;
  int total = E1 + E2 + E3;
  if (i >= total) return;
  int p = (i >> 8) & 7;
  if (i < E1) {
    int d = c1[i]; rnk1[i] = atomicAdd(&cp1[p * n1 + d], 1);
  } else if (i < E1 + E2) {
    int j = i - E1;
    int d = c2[j]; rnk2[j] = atomicAdd(&cp2[p * n2 + d], 1);
  } else {
    int j = i - E1 - E2;
    int d = c3[j]; rnk3[j] = atomicAdd(&cp3[p * n3 + d], 1);
  }
}

// parallel per-node partition merge (coalesced per partition)
__global__ void merge3_kernel(int* cp1, int* c1, int n1,
                              int* cp2, int* c2, int n2,
                              int* cp3, int* c3, int n3) {
  int i = blockIdx.x * blockDim.x + threadIdx.x;
  int total = n1 + n2 + n3;
  if (i >= total) return;
  int *cp, *c; int n, d;
  if (i < n1) { cp = cp1; c = c1; n = n1; d = i; }
  else if (i < n1 + n2) { cp = cp2; c = c2; n = n2; d = i - n1; }
  else { cp = cp3; c = c3; n = n3; d = i - n1 - n2; }
  int s = 0;
#pragma unroll
  for (int p = 0; p < 8; ++p) { int t = cp[p * n + d]; cp[p * n + d] = s; s += t; }
  c[d] = s;
}

__global__ __launch_bounds__(1024) void scan3_kernel(
    const int* cntA, int nA, int* ptrA,
    const int* cntB, int nB, int* ptrB,
    const int* cntC, int nC, int* ptrC) {
  const int* cnt; int n; int* ptr;
  if (blockIdx.x == 0) { cnt = cntA; n = nA; ptr = ptrA; }
  else if (blockIdx.x == 1) { cnt = cntB; n = nB; ptr = ptrB; }
  else { cnt = cntC; n = nC; ptr = ptrC; }
  __shared__ int part[1024];
  int t = threadIdx.x;
  int ch = (n + 1023) / 1024;
  int beg = t * ch, end = min(beg + ch, n);
  int s = 0;
  for (int i = beg; i < end; ++i) s += cnt[i];
  part[t] = s;
  __syncthreads();
  for (int off = 1; off < 1024; off <<= 1) {
    int v = (t >= off) ? part[t - off] : 0;
    __syncthreads();
    part[t] += v;
    __syncthreads();
  }
  int run = (t == 0) ? 0 : part[t - 1];
  for (int i = beg; i < end; ++i) { ptr[i] = run; run += cnt[i]; }
  if (t == 1023) ptr[n] = part[1023];
}

// ---------------------------------------------------------------------------
// scatter + (independent) dote + spc96/h0 prep, one launch.
// blocks [0,3125): scatter; [3125,3130): dote; rest: prep.
// ---------------------------------------------------------------------------
struct DoteArgs { const float* We[5]; const float* ae[5]; float* dotes; };
struct PrepArgs {
  const float* mean; const float* stdv; const void* mask; const int* flag;
  const float* sx; const float* sg; float* spc96; float* h0;
};

__global__ void scatter3x_kernel(
    const int* r1, const int* c1, const float* e1, int E1, const int* p1, const int* cp1, const int* k1, int n1, int* s1, float* a1,
    const int* r2, const int* c2, const float* e2, int E2, const int* p2, const int* cp2, const int* k2, int n2, int* s2, float* a2,
    const int* r3, const int* c3, const float* e3, int E3, const int* p3, const int* cp3, const int* k3, int n3, int* s3, float* a3,
    DoteArgs da, PrepArgs pa) {
  const int NB_SC = (ESS + EBIP + ESP + 255) / 256;   // 3125
  int b = blockIdx.x, t = threadIdx.x;
  if (b < NB_SC) {
    int i = b * 256 + t;
    if (i >= E1 + E2 + E3) return;
    int p = (i >> 8) & 7;
    if (i < E1) {
      int d = c1[i];
      int pos = p1[d] + cp1[p * n1 + d] + k1[i];
      s1[pos] = r1[i]; a1[pos] = e1[i];
    } else if (i < E1 + E2) {
      int j = i - E1;
      int d = c2[j];
      int pos = p2[d] + cp2[p * n2 + d] + k2[j];
      s2[pos] = r2[j]; a2[pos] = e2[j];
    } else {
      int j = i - E1 - E2;
      int d = c3[j];
      int pos = p3[d] + cp3[p * n3 + d] + k3[j];
      s3[pos] = r3[j]; a3[pos] = e3[j];
    }
  } else if (b < NB_SC + 5) {
    int lb = b - NB_SC;
    int n = (lb == 2) ? 64 : 256;
    if (t < n) {
      float p = wave_red_sum(da.We[lb][t] * da.ae[lb][t]);
      if ((t & 63) == 0) da.dotes[lb * 4 + (t >> 6)] = p;
    }
  } else {
    const long totA = (long)NSP * 96;
    const long totB = (long)NSPAT * 16;
    long i = (long)(b - NB_SC - 5) * 256 + t;
    if (i >= totA + totB) return;
    int mode = *pa.flag;
    if (i < totA) {
      int n = (int)(i / 96), c = (int)(i % 96);
      float v;
      if (c < 32) v = pa.mean[(long)n * 32 + c];
      else if (c < 64) v = pa.stdv[(long)n * 32 + (c - 32)];
      else {
        long j = (long)n * 32 + (c - 64);
        int mv;
        if (mode == 0) mv = ((const int*)pa.mask)[j];
        else if (mode == 2) mv = (((const float*)pa.mask)[j] != 0.0f);
        else mv = (int)((const unsigned char*)pa.mask)[j];
        v = mv ? 0.f : 1.f;   // vis = ~mask
      }
      pa.spc96[i] = v;
    } else {
      long k = i - totA;
      int n = (int)(k / 16), c = (int)(k % 16);
      pa.h0[k] = (c < 12) ? pa.sx[(long)n * 12 + c] : pa.sg[(long)n * 4 + (c - 12)];
    }
  }
}

struct XSrc { const float* p[5]; int w[5]; int n; };
struct PJob {
  XSrc xs; int M, K;
  const float* W; const float* bias; int mode;
  const float* a_s; const float* a_d;
  float* al_s; float* al_d;
  float* Y; float* Y2;
};
struct LeafArgs {
  const int* ss_ptr; const float* ss_cea; float* ss_lea;
  const int* pp_ptr; const float* pp_cea; float* pp_lea;
};

// ---------------------------------------------------------------------------
// NOUT=64 projection body, tiled: BR=32 rows/block, KC=32.  4 cols x 2 rows.
// mode: 0 plain (skip store if Y null), 1 bias+relu, 2 final split.
// ---------------------------------------------------------------------------
__device__ __forceinline__ void proj64_body(const PJob& J, int bid,
                                            float* wl, float* xl) {
  constexpr int KC = 32;
  constexpr int BR = 32;
  constexpr int KCP = 36;
  int t = threadIdx.x;
  long row0 = (long)bid * BR;
  if (row0 >= J.M) return;
  int cg = t & 15, rg = t >> 4;
  int c0 = cg * 4;

  float acc[2][4];
#pragma unroll
  for (int r = 0; r < 2; ++r)
#pragma unroll
    for (int j = 0; j < 4; ++j) acc[r][j] = 0.f;

  for (int k0 = 0; k0 < J.K; k0 += KC) {
    int seg = 0; int base = 0;
    while (k0 >= base + J.xs.w[seg]) { base += J.xs.w[seg]; ++seg; }
    const float* Xp = J.xs.p[seg];
    int stride = J.xs.w[seg];
    int kloc = k0 - base;

    __syncthreads();
    {
      const float4* ws = (const float4*)(J.W + (long)k0 * 64);
      float4* wd = (float4*)wl;
      wd[t] = ws[t];
      wd[t + 256] = ws[t + 256];
    }
    {
      int r = t >> 3, kq = (t & 7) * 4;
      long rr = row0 + r; if (rr >= J.M) rr = J.M - 1;
      float4 v = *(const float4*)(Xp + rr * stride + kloc + kq);
      *(float4*)(xl + r * KCP + kq) = v;
    }
    __syncthreads();

    for (int kg = 0; kg < KC; kg += 4) {
      float4 w0 = *(const float4*)(wl + (kg + 0) * 64 + c0);
      float4 w1 = *(const float4*)(wl + (kg + 1) * 64 + c0);
      float4 w2 = *(const float4*)(wl + (kg + 2) * 64 + c0);
      float4 w3 = *(const float4*)(wl + (kg + 3) * 64 + c0);
#pragma unroll
      for (int r = 0; r < 2; ++r) {
        float4 xv = *(const float4*)(xl + (rg * 2 + r) * KCP + kg);
        acc[r][0] = fmaf(xv.x, w0.x, acc[r][0]);
        acc[r][1] = fmaf(xv.x, w0.y, acc[r][1]);
        acc[r][2] = fmaf(xv.x, w0.z, acc[r][2]);
        acc[r][3] = fmaf(xv.x, w0.w, acc[r][3]);
        acc[r][0] = fmaf(xv.y, w1.x, acc[r][0]);
        acc[r][1] = fmaf(xv.y, w1.y, acc[r][1]);
        acc[r][2] = fmaf(xv.y, w1.z, acc[r][2]);
        acc[r][3] = fmaf(xv.y, w1.w, acc[r][3]);
        acc[r][0] = fmaf(xv.z, w2.x, acc[r][0]);
        acc[r][1] = fmaf(xv.z, w2.y, acc[r][1]);
        acc[r][2] = fmaf(xv.z, w2.z, acc[r][2]);
        acc[r][3] = fmaf(xv.z, w2.w, acc[r][3]);
        acc[r][0] = fmaf(xv.w, w3.x, acc[r][0]);
        acc[r][1] = fmaf(xv.w, w3.y, acc[r][1]);
        acc[r][2] = fmaf(xv.w, w3.z, acc[r][2]);
        acc[r][3] = fmaf(xv.w, w3.w, acc[r][3]);
      }
    }
  }

  float4 bv = make_float4(0.f, 0.f, 0.f, 0.f);
  float4 asv = make_float4(0.f, 0.f, 0.f, 0.f);
  float4 adv = make_float4(0.f, 0.f, 0.f, 0.f);
  if (J.bias) bv = *(const float4*)(J.bias + c0);
  if (J.a_s) asv = *(const float4*)(J.a_s + c0);
  if (J.a_d) adv = *(const float4*)(J.a_d + c0);

#pragma unroll
  for (int r = 0; r < 2; ++r) {
    long m = row0 + rg * 2 + r;
    bool ok = m < J.M;
    float v0 = acc[r][0] + bv.x, v1 = acc[r][1] + bv.y;
    float v2 = acc[r][2] + bv.z, v3 = acc[r][3] + bv.w;
    if (J.mode == 1) {
      if (ok)
        *(float4*)(J.Y + m * 64 + c0) = make_float4(
            fmaxf(v0, 0.f), fmaxf(v1, 0.f), fmaxf(v2, 0.f), fmaxf(v3, 0.f));
    } else if (J.mode == 2) {
      if (ok) {
        if (c0 < 32) {
          *(float4*)(J.Y + m * 32 + c0) = make_float4(v0, v1, v2, v3);
        } else {
          float4 o;
          o.x = fmaxf(v0, 0.f) + log1pf(__expf(-fabsf(v0))) + 1e-6f;
          o.y = fmaxf(v1, 0.f) + log1pf(__expf(-fabsf(v1))) + 1e-6f;
          o.z = fmaxf(v2, 0.f) + log1pf(__expf(-fabsf(v2))) + 1e-6f;
          o.w = fmaxf(v3, 0.f) + log1pf(__expf(-fabsf(v3))) + 1e-6f;
          *(float4*)(J.Y2 + m * 32 + (c0 - 32)) = o;
        }
      }
    } else if (ok && J.Y) {
      *(float4*)(J.Y + m * 64 + c0) = make_float4(v0, v1, v2, v3);
    }
    if (J.a_s) {
      float s = acc[r][0] * asv.x + acc[r][1] * asv.y + acc[r][2] * asv.z + acc[r][3] * asv.w;
      s += __shfl_xor(s, 1); s += __shfl_xor(s, 2);
      s += __shfl_xor(s, 4); s += __shfl_xor(s, 8);
      if (ok && cg == 0) J.al_s[m] = s;
    }
    if (J.a_d) {
      float s = acc[r][0] * adv.x + acc[r][1] * adv.y + acc[r][2] * adv.z + acc[r][3] * adv.w;
      s += __shfl_xor(s, 1); s += __shfl_xor(s, 2);
      s += __shfl_xor(s, 4); s += __shfl_xor(s, 8);
      if (ok && cg == 0) J.al_d[m] = s;
    }
  }
}

// two NOUT=64 jobs + optional leafin tail blocks, one launch
__global__ __launch_bounds__(256) void proj64x2l_kernel(PJob j0, PJob j1,
                                                        int nb0, int nb1,
                                                        LeafArgs la) {
  __shared__ float wl[32 * 64];
  __shared__ float xl[32 * 36];
  int b = blockIdx.x, t = threadIdx.x;
  if (b < nb0) {
    proj64_body(j0, b, wl, xl);
  } else if (b < nb0 + nb1) {
    proj64_body(j1, b - nb0, wl, xl);
  } else {
    int i = (b - nb0 - nb1) * 256 + t;
    if (i >= NSPAT + NSP) return;
    const int* ptr; const float* cea; float* lea; int d;
    if (i < NSPAT) { ptr = la.ss_ptr; cea = la.ss_cea; lea = la.ss_lea; d = i; }
    else { ptr = la.pp_ptr; cea = la.pp_cea; lea = la.pp_lea; d = i - NSPAT; }
    int e0 = ptr[d], e1 = ptr[d + 1];
    float s = 0.f;
    for (int e = e0; e < e1; ++e) s += cea[e];
    lea[d] = s / (float)max(e1 - e0, 1);
  }
}

// ---------------------------------------------------------------------------
// NOUT=256 projection (tiled, BR=32): X and W staged in LDS.  bf16 out.
// ---------------------------------------------------------------------------
__global__ __launch_bounds__(256) void proj_kernel(
    XSrc xsrc, int M, int K,
    const float* __restrict__ W,
    const float* __restrict__ a_s, const float* __restrict__ a_d,
    float* __restrict__ al_s, float* __restrict__ al_d,
    unsigned short* __restrict__ Y) {
  constexpr int KC = 32;
  constexpr int RPT = 8;
  constexpr int BR = 32;
  constexpr int KCP = 36;
  constexpr int H = 4;
  __shared__ float wl[KC * 256];
  __shared__ float xl[BR * KCP];

  int t = threadIdx.x;
  int cg = t & 63, rg = t >> 6;
  int c0 = cg * 4;
  long row0 = (long)blockIdx.x * BR;

  float acc[RPT][4];
#pragma unroll
  for (int r = 0; r < RPT; ++r)
#pragma unroll
    for (int j = 0; j < 4; ++j) acc[r][j] = 0.f;

  for (int k0 = 0; k0 < K; k0 += KC) {
    int kc = min(KC, K - k0);
    int seg = 0; int base = 0;
    while (k0 >= base + xsrc.w[seg]) { base += xsrc.w[seg]; ++seg; }
    const float* Xp = xsrc.p[seg];
    int stride = xsrc.w[seg];
    int kloc = k0 - base;

    __syncthreads();
    {
      const float4* wsrc = (const float4*)(W + (long)k0 * 256);
      float4* wdst = (float4*)wl;
      for (int i = t; i < (kc * 256) >> 2; i += 256) wdst[i] = wsrc[i];
    }
    for (int i = t; i < BR * 8; i += 256) {
      int r = i >> 3, kq = (i & 7) * 4;
      if (kq < kc) {
        long rr = row0 + r; if (rr >= M) rr = M - 1;
        float4 v = *(const float4*)(Xp + rr * stride + kloc + kq);
        *(float4*)(xl + r * KCP + kq) = v;
      }
    }
    __syncthreads();

    for (int kg = 0; kg < kc; kg += 4) {
      float4 w0 = *(const float4*)(wl + (kg + 0) * 256 + c0);
      float4 w1 = *(const float4*)(wl + (kg + 1) * 256 + c0);
      float4 w2 = *(const float4*)(wl + (kg + 2) * 256 + c0);
      float4 w3 = *(const float4*)(wl + (kg + 3) * 256 + c0);
      float4 xv[RPT];
#pragma unroll
      for (int r = 0; r < RPT; ++r)
        xv[r] = *(const float4*)(xl + (rg * RPT + r) * KCP + kg);
#pragma unroll
      for (int r = 0; r < RPT; ++r) {
        acc[r][0] = fmaf(xv[r].x, w0.x, acc[r][0]);
        acc[r][1] = fmaf(xv[r].x, w0.y, acc[r][1]);
        acc[r][2] = fmaf(xv[r].x, w0.z, acc[r][2]);
        acc[r][3] = fmaf(xv[r].x, w0.w, acc[r][3]);
        acc[r][0] = fmaf(xv[r].y, w1.x, acc[r][0]);
        acc[r][1] = fmaf(xv[r].y, w1.y, acc[r][1]);
        acc[r][2] = fmaf(xv[r].y, w1.z, acc[r][2]);
        acc[r][3] = fmaf(xv[r].y, w1.w, acc[r][3]);
        acc[r][0] = fmaf(xv[r].z, w2.x, acc[r][0]);
        acc[r][1] = fmaf(xv[r].z, w2.y, acc[r][1]);
        acc[r][2] = fmaf(xv[r].z, w2.z, acc[r][2]);
        acc[r][3] = fmaf(xv[r].z, w2.w, acc[r][3]);
        acc[r][0] = fmaf(xv[r].w, w3.x, acc[r][0]);
        acc[r][1] = fmaf(xv[r].w, w3.y, acc[r][1]);
        acc[r][2] = fmaf(xv[r].w, w3.z, acc[r][2]);
        acc[r][3] = fmaf(xv[r].w, w3.w, acc[r][3]);
      }
    }
  }

  float4 asv = *(const float4*)(a_s + c0);
  float4 adv = *(const float4*)(a_d + c0);

#pragma unroll
  for (int r = 0; r < RPT; ++r) {
    long m = row0 + (long)rg * RPT + r;
    bool ok = m < M;
    if (ok) {
      ushort4 o;
      o.x = f2bf(acc[r][0]); o.y = f2bf(acc[r][1]);
      o.z = f2bf(acc[r][2]); o.w = f2bf(acc[r][3]);
      *(ushort4*)(Y + m * 256 + c0) = o;
    }
    float s = acc[r][0] * asv.x + acc[r][1] * asv.y + acc[r][2] * asv.z + acc[r][3] * asv.w;
    s += __shfl_xor(s, 1); s += __shfl_xor(s, 2);
    s += __shfl_xor(s, 4); s += __shfl_xor(s, 8);
    if (ok && (cg & 15) == 0) al_s[m * H + (c0 >> 6)] = s;
    float d = acc[r][0] * adv.x + acc[r][1] * adv.y + acc[r][2] * adv.z + acc[r][3] * adv.w;
    d += __shfl_xor(d, 1); d += __shfl_xor(d, 2);
    d += __shfl_xor(d, 4); d += __shfl_xor(d, 8);
    if (ok && (cg & 15) == 0) al_d[m * H + (c0 >> 6)] = d;
  }
}

// ---------------------------------------------------------------------------
// Fused GAT layer, H=4 C=64, bf16 hs: one wave per node covers all heads.
// ---------------------------------------------------------------------------
__device__ __forceinline__ void fma4_bf(float4& a, float al, ushort4 u) {
  a.x = fmaf(al, bf2f(u.x), a.x); a.y = fmaf(al, bf2f(u.y), a.y);
  a.z = fmaf(al, bf2f(u.z), a.z); a.w = fmaf(al, bf2f(u.w), a.w);
}
__device__ __forceinline__ void scale4(float4& a, float s) {
  a.x *= s; a.y *= s; a.z *= s; a.w *= s;
}

template <bool SELFLOOP>
__global__ __launch_bounds__(256) void gat4_fused(
    int Nd, const int* __restrict__ dptr, const int* __restrict__ csr_src,
    const float* __restrict__ csr_ea, const float* __restrict__ al_s,
    const float* __restrict__ al_d, const float* __restrict__ dote,
    const float* __restrict__ loop_ea, const unsigned short* __restrict__ hs,
    const float* __restrict__ bias, float* __restrict__ out) {
  int wave = threadIdx.x >> 6, lane = threadIdx.x & 63;
  int n = blockIdx.x * 4 + wave;
  if (n >= Nd) return;
  int h = lane >> 4;
  float ald = al_d[(long)n * 4 + h];
  float de = dote[h];
  int e0 = dptr[n], e1 = dptr[n + 1];
  float m0 = -INFINITY, d0 = 0.f;
  float4 a0 = make_float4(0.f, 0.f, 0.f, 0.f);
  if (SELFLOOP) {
    float l = al_s[(long)n * 4 + h] + ald + loop_ea[n] * de;
    l = (l > 0.f) ? l : 0.2f * l;
    m0 = l; d0 = 1.f;
    ushort4 u = *(const ushort4*)(hs + (long)n * 256 + lane * 4);
    a0.x = bf2f(u.x); a0.y = bf2f(u.y); a0.z = bf2f(u.z); a0.w = bf2f(u.w);
  }
  float m1 = -INFINITY, d1 = 0.f;
  float4 a1 = make_float4(0.f, 0.f, 0.f, 0.f);
  int e = e0;
  for (; e + 2 <= e1; e += 2) {
    int s0 = csr_src[e], s1 = csr_src[e + 1];
    float l0 = al_s[(long)s0 * 4 + h] + ald + csr_ea[e] * de;
    float l1 = al_s[(long)s1 * 4 + h] + ald + csr_ea[e + 1] * de;
    l0 = (l0 > 0.f) ? l0 : 0.2f * l0;
    l1 = (l1 > 0.f) ? l1 : 0.2f * l1;
    ushort4 u0 = *(const ushort4*)(hs + (long)s0 * 256 + lane * 4);
    ushort4 u1 = *(const ushort4*)(hs + (long)s1 * 256 + lane * 4);
    if (l0 > m0) { float sc = __expf(m0 - l0); d0 *= sc; scale4(a0, sc); m0 = l0; }
    float ex0 = __expf(l0 - m0);
    d0 += ex0;
    fma4_bf(a0, ex0, u0);
    if (l1 > m1) { float sc = __expf(m1 - l1); d1 *= sc; scale4(a1, sc); m1 = l1; }
    float ex1 = __expf(l1 - m1);
    d1 += ex1;
    fma4_bf(a1, ex1, u1);
  }
  if (e < e1) {
    int s0 = csr_src[e];
    float l0 = al_s[(long)s0 * 4 + h] + ald + csr_ea[e] * de;
    l0 = (l0 > 0.f) ? l0 : 0.2f * l0;
    ushort4 u0 = *(const ushort4*)(hs + (long)s0 * 256 + lane * 4);
    if (l0 > m0) { float sc = __expf(m0 - l0); d0 *= sc; scale4(a0, sc); m0 = l0; }
    float ex0 = __expf(l0 - m0);
    d0 += ex0;
    fma4_bf(a0, ex0, u0);
  }
  if (m1 != -INFINITY) {
    float M = fmaxf(m0, m1);
    float sA = (m0 == -INFINITY) ? 0.f : __expf(m0 - M);
    float sB = __expf(m1 - M);
    d0 = d0 * sA + d1 * sB;
    a0.x = a0.x * sA + a1.x * sB; a0.y = a0.y * sA + a1.y * sB;
    a0.z = a0.z * sA + a1.z * sB; a0.w = a0.w * sA + a1.w * sB;
  }
  float inv = 1.f / (d0 + 1e-16f);
  scale4(a0, inv);
  a0.x += __shfl_xor(a0.x, 16); a0.y += __shfl_xor(a0.y, 16);
  a0.z += __shfl_xor(a0.z, 16); a0.w += __shfl_xor(a0.w, 16);
  a0.x += __shfl_xor(a0.x, 32); a0.y += __shfl_xor(a0.y, 32);
  a0.z += __shfl_xor(a0.z, 32); a0.w += __shfl_xor(a0.w, 32);
  if (lane < 16) {
    float4 b = *(const float4*)(bias + lane * 4);
    float4 o;
    o.x = fmaxf(a0.x * 0.25f + b.x, 0.f);
    o.y = fmaxf(a0.y * 0.25f + b.y, 0.f);
    o.z = fmaxf(a0.z * 0.25f + b.z, 0.f);
    o.w = fmaxf(a0.w * 0.25f + b.w, 0.f);
    *(float4*)(out + (long)n * 64 + lane * 4) = o;
  }
}

// Fused GAT layer, H=1 C=64, fp32 hs (bipartite): wave per node, lane=channel.
__global__ __launch_bounds__(256) void gat1_fused(
    int Nd, const int* __restrict__ dptr, const int* __restrict__ csr_src,
    const float* __restrict__ csr_ea, const float* __restrict__ al_s,
    const float* __restrict__ al_d, const float* __restrict__ dote,
    const float* __restrict__ hs, const float* __restrict__ bias,
    float* __restrict__ out) {
  int wave = threadIdx.x >> 6, lane = threadIdx.x & 63;
  int n = blockIdx.x * 4 + wave;
  if (n >= Nd) return;
  float ald = al_d[n];
  float de = dote[0];
  int e0 = dptr[n], e1 = dptr[n + 1];
  float m0 = -INFINITY, d0 = 0.f, acc0 = 0.f;
  float m1 = -INFINITY, d1 = 0.f, acc1 = 0.f;
  int e = e0;
  for (; e + 2 <= e1; e += 2) {
    int s0 = csr_src[e], s1 = csr_src[e + 1];
    float l0 = al_s[s0] + ald + csr_ea[e] * de;
    float l1 = al_s[s1] + ald + csr_ea[e + 1] * de;
    l0 = (l0 > 0.f) ? l0 : 0.2f * l0;
    l1 = (l1 > 0.f) ? l1 : 0.2f * l1;
    float h0 = hs[(long)s0 * 64 + lane];
    float h1 = hs[(long)s1 * 64 + lane];
    if (l0 > m0) { float sc = __expf(m0 - l0); d0 *= sc; acc0 *= sc; m0 = l0; }
    float ex0 = __expf(l0 - m0);
    d0 += ex0; acc0 = fmaf(ex0, h0, acc0);
    if (l1 > m1) { float sc = __expf(m1 - l1); d1 *= sc; acc1 *= sc; m1 = l1; }
    float ex1 = __expf(l1 - m1);
    d1 += ex1; acc1 = fmaf(ex1, h1, acc1);
  }
  if (e < e1) {
    int s0 = csr_src[e];
    float l0 = al_s[s0] + ald + csr_ea[e] * de;
    l0 = (l0 > 0.f) ? l0 : 0.2f * l0;
    float h0 = hs[(long)s0 * 64 + lane];
    if (l0 > m0) { float sc = __expf(m0 - l0); d0 *= sc; acc0 *= sc; m0 = l0; }
    float ex0 = __expf(l0 - m0);
    d0 += ex0; acc0 = fmaf(ex0, h0, acc0);
  }
  if (m1 != -INFINITY) {
    float M = fmaxf(m0, m1);
    float sA = (m0 == -INFINITY) ? 0.f : __expf(m0 - M);
    float sB = __expf(m1 - M);
    d0 = d0 * sA + d1 * sB;
    acc0 = acc0 * sA + acc1 * sB;
  }
  float o = acc0 / (d0 + 1e-16f);
  out[(long)n * 64 + lane] = fmaxf(o + bias[lane], 0.f);
}

// ---------------------------------------------------------------------------
extern "C" void kernel_launch(void* const* d_in, const int* in_sizes, int n_in,
                              void* d_out, int out_size, void* d_ws, size_t ws_size,
                              hipStream_t stream) {
  const float* sp_mean = (const float*)d_in[0];
  const float* sp_std  = (const float*)d_in[1];
  const void*  nanmask = d_in[2];
  const float* sp_gen  = (const float*)d_in[3];
  const float* sp_phy  = (const float*)d_in[4];
  const float* spat_x  = (const float*)d_in[5];
  const float* spat_g  = (const float*)d_in[6];
  const int*   ss_ei   = (const int*)d_in[7];
  const float* ss_ea   = (const float*)d_in[8];
  const int*   bip_ei  = (const int*)d_in[9];
  const float* bip_ea  = (const float*)d_in[10];
  const int*   sp_ei   = (const int*)d_in[11];
  const float* sp_ea   = (const float*)d_in[12];
  const float* sg0_W = (const float*)d_in[13]; const float* sg0_as = (const float*)d_in[14];
  const float* sg0_ad = (const float*)d_in[15]; const float* sg0_ae = (const float*)d_in[16];
  const float* sg0_We = (const float*)d_in[17]; const float* sg0_b = (const float*)d_in[18];
  const float* sg1_W = (const float*)d_in[19]; const float* sg1_as = (const float*)d_in[20];
  const float* sg1_ad = (const float*)d_in[21]; const float* sg1_ae = (const float*)d_in[22];
  const float* sg1_We = (const float*)d_in[23]; const float* sg1_b = (const float*)d_in[24];
  const float* pg0_W = (const float*)d_in[25]; const float* pg0_as = (const float*)d_in[26];
  const float* pg0_ad = (const float*)d_in[27]; const float* pg0_ae = (const float*)d_in[28];
  const float* pg0_We = (const float*)d_in[29]; const float* pg0_b = (const float*)d_in[30];
  const float* pg1_W = (const float*)d_in[31]; const float* pg1_as = (const float*)d_in[32];
  const float* pg1_ad = (const float*)d_in[33]; const float* pg1_ae = (const float*)d_in[34];
  const float* pg1_We = (const float*)d_in[35]; const float* pg1_b = (const float*)d_in[36];
  const float* bp_Ws = (const float*)d_in[37]; const float* bp_Wd = (const float*)d_in[38];
  const float* bp_as = (const float*)d_in[39]; const float* bp_ad = (const float*)d_in[40];
  const float* bp_ae = (const float*)d_in[41]; const float* bp_We = (const float*)d_in[42];
  const float* bp_b  = (const float*)d_in[43];
  const float* sl_W  = (const float*)d_in[44]; const float* sl_b  = (const float*)d_in[45];
  const float* fc_W  = (const float*)d_in[46]; const float* fc_b  = (const float*)d_in[47];

  // ---- workspace layout ----
  char* wsb = (char*)d_ws;
  size_t off = 0;
  auto A = [&](size_t nbytes) -> void* {
    void* p = wsb + off;
    off += (nbytes + 255) & ~(size_t)255;
    return p;
  };
  int* ss_cp = (int*)A((size_t)8 * NSPAT * 4);
  int* bp_cp = (int*)A((size_t)8 * NSP * 4);
  int* pp_cp = (int*)A((size_t)8 * NSP * 4);
  size_t zbytes = off;
  int*   ss_cnt = (int*)A((NSPAT + 1) * 4);
  int*   bp_cnt = (int*)A((NSP + 1) * 4);
  int*   pp_cnt = (int*)A((NSP + 1) * 4);
  int*   flag  = (int*)A(4);
  float* dotes = (float*)A(5 * 4 * sizeof(float));
  float* alS   = (float*)A((size_t)NSP * 4 * 4);
  float* alD   = (float*)A((size_t)NSP * 4 * 4);
  float* alSb  = (float*)A((size_t)NSPAT * 4);
  float* alDb  = (float*)A((size_t)NSP * 4);
  float* spc96 = (float*)A((size_t)NSP * 96 * 4);
  float* sp_in = (float*)A((size_t)NSP * 64 * 4);
  float* h0    = (float*)A((size_t)NSPAT * 16 * 4);
  float* h_a   = (float*)A((size_t)NSPAT * 64 * 4);
  float* h_b   = (float*)A((size_t)NSPAT * 64 * 4);
  float* HS    = (float*)A((size_t)NSP * 256 * 4);   // bf16 hs rows
  float* sts   = (float*)A((size_t)NSP * 64 * 4);
  float* x1    = (float*)A((size_t)NSP * 64 * 4);
  int*   ss_ptr = (int*)A((NSPAT + 1) * 4);
  int*   ss_src = (int*)A((size_t)ESS * 4);
  float* ss_cea = (float*)A((size_t)ESS * 4);
  int*   ss_rnk = (int*)A((size_t)ESS * 4);
  float* ss_lea = (float*)A((size_t)NSPAT * 4);
  int*   bp_ptr = (int*)A((NSP + 1) * 4);
  int*   bp_src = (int*)A((size_t)EBIP * 4);
  float* bp_cea = (float*)A((size_t)EBIP * 4);
  int*   bp_rnk = (int*)A((size_t)EBIP * 4);
  int*   pp_ptr = (int*)A((NSP + 1) * 4);
  int*   pp_src = (int*)A((size_t)ESP * 4);
  float* pp_cea = (float*)A((size_t)ESP * 4);
  int*   pp_rnk = (int*)A((size_t)ESP * 4);
  float* pp_lea = (float*)A((size_t)NSP * 4);
  (void)ws_size; (void)in_sizes; (void)n_in; (void)out_size;

  const int TB = 256;
  hipMemsetAsync(wsb, 0, zbytes, stream);

  // ---- graph builds: count(+detect) -> merge -> scan ----
  count3_kernel<<<cdiv_host(ESS + EBIP + ESP, TB) + 1, TB, 0, stream>>>(
      ss_ei + ESS, ESS, ss_cp, ss_rnk, NSPAT,
      bip_ei + EBIP, EBIP, bp_cp, bp_rnk, NSP,
      sp_ei + ESP, ESP, pp_cp, pp_rnk, NSP,
      (const unsigned int*)nanmask, flag);
  merge3_kernel<<<cdiv_host(NSPAT + NSP + NSP, TB), TB, 0, stream>>>(
      ss_cp, ss_cnt, NSPAT, bp_cp, bp_cnt, NSP, pp_cp, pp_cnt, NSP);
  scan3_kernel<<<3, 1024, 0, stream>>>(ss_cnt, NSPAT, ss_ptr, bp_cnt, NSP, bp_ptr, pp_cnt, NSP, pp_ptr);

  // ---- scatter + dote + spc96/h0 prep (one launch) ----
  {
    DoteArgs da{};
    da.We[0] = sg0_We; da.ae[0] = sg0_ae;
    da.We[1] = sg1_We; da.ae[1] = sg1_ae;
    da.We[2] = bp_We;  da.ae[2] = bp_ae;
    da.We[3] = pg0_We; da.ae[3] = pg0_ae;
    da.We[4] = pg1_We; da.ae[4] = pg1_ae;
    da.dotes = dotes;
    PrepArgs pa{ sp_mean, sp_std, nanmask, flag, spat_x, spat_g, spc96, h0 };
    int nb = cdiv_host(ESS + EBIP + ESP, TB) + 5 +
             cdiv_host((long)NSP * 96 + (long)NSPAT * 16, TB);
    scatter3x_kernel<<<nb, TB, 0, stream>>>(
        ss_ei, ss_ei + ESS, ss_ea, ESS, ss_ptr, ss_cp, ss_rnk, NSPAT, ss_src, ss_cea,
        bip_ei, bip_ei + EBIP, bip_ea, EBIP, bp_ptr, bp_cp, bp_rnk, NSP, bp_src, bp_cea,
        sp_ei, sp_ei + ESP, sp_ea, ESP, pp_ptr, pp_cp, pp_rnk, NSP, pp_src, pp_cea,
        da, pa);
  }

  // ---- sl proj + bp_Wd proj + leafin (one launch) ----
  {
    PJob j0{}; j0.xs.p[0] = spc96; j0.xs.w[0] = 96; j0.xs.p[1] = sp_gen; j0.xs.w[1] = 64;
    j0.xs.p[2] = sp_phy; j0.xs.w[2] = 128; j0.xs.n = 3;
    j0.M = NSP; j0.K = 288; j0.W = sl_W; j0.bias = sl_b; j0.mode = 1; j0.Y = sp_in;
    PJob j1{}; j1.xs.p[0] = sp_gen; j1.xs.w[0] = 64; j1.xs.p[1] = sp_phy; j1.xs.w[1] = 128;
    j1.xs.n = 2;
    j1.M = NSP; j1.K = 192; j1.W = bp_Wd; j1.mode = 0; j1.a_d = bp_ad; j1.al_d = alDb;
    LeafArgs la{ ss_ptr, ss_cea, ss_lea, pp_ptr, pp_cea, pp_lea };
    int nb0 = cdiv_host(NSP, 32), nb1 = cdiv_host(NSP, 32);
    int nbl = cdiv_host(NSPAT + NSP, TB);
    proj64x2l_kernel<<<nb0 + nb1 + nbl, TB, 0, stream>>>(j0, j1, nb0, nb1, la);
  }

  // ---- spatial GNN ----
  {
    XSrc xs{}; xs.p[0] = h0; xs.w[0] = 16; xs.n = 1;
    proj_kernel<<<cdiv_host(NSPAT, 32), TB, 0, stream>>>(xs, NSPAT, 16, sg0_W,
        sg0_as, sg0_ad, alS, alD, (unsigned short*)HS);
  }
  gat4_fused<true><<<cdiv_host(NSPAT, 4), TB, 0, stream>>>(
      NSPAT, ss_ptr, ss_src, ss_cea, alS, alD, dotes + 0, ss_lea,
      (const unsigned short*)HS, sg0_b, h_a);
  {
    XSrc xs{}; xs.p[0] = h_a; xs.w[0] = 64; xs.n = 1;
    proj_kernel<<<cdiv_host(NSPAT, 32), TB, 0, stream>>>(xs, NSPAT, 64, sg1_W,
        sg1_as, sg1_ad, alS, alD, (unsigned short*)HS);
  }
  gat4_fused<true><<<cdiv_host(NSPAT, 4), TB, 0, stream>>>(
      NSPAT, ss_ptr, ss_src, ss_cea, alS, alD, dotes + 4, ss_lea,
      (const unsigned short*)HS, sg1_b, h_b);

  // ---- bipartite GAT (spatial -> species), H=1, concat ----
  {
    PJob j0{}; j0.xs.p[0] = h_b; j0.xs.w[0] = 64; j0.xs.n = 1;
    j0.M = NSPAT; j0.K = 64; j0.W = bp_Ws; j0.mode = 0;
    j0.a_s = bp_as; j0.al_s = alSb; j0.Y = h_a;    // h_a := hs_src (fp32)
    LeafArgs la{ ss_ptr, ss_cea, ss_lea, pp_ptr, pp_cea, pp_lea };
    int nb0 = cdiv_host(NSPAT, 32);
    proj64x2l_kernel<<<nb0, TB, 0, stream>>>(j0, j0, nb0, 0, la);
  }
  gat1_fused<<<cdiv_host(NSP, 4), TB, 0, stream>>>(
      NSP, bp_ptr, bp_src, bp_cea, alSb, alDb, dotes + 8, h_a, bp_b, sts);

  // ---- species GNN ----
  {
    XSrc xs{}; xs.p[0] = sts; xs.w[0] = 64; xs.p[1] = sp_in; xs.w[1] = 64; xs.n = 2;
    proj_kernel<<<cdiv_host(NSP, 32), TB, 0, stream>>>(xs, NSP, 128, pg0_W,
        pg0_as, pg0_ad, alS, alD, (unsigned short*)HS);
  }
  gat4_fused<true><<<cdiv_host(NSP, 4), TB, 0, stream>>>(
      NSP, pp_ptr, pp_src, pp_cea, alS, alD, dotes + 12, pp_lea,
      (const unsigned short*)HS, pg0_b, x1);
  {
    XSrc xs{}; xs.p[0] = x1; xs.w[0] = 64; xs.n = 1;
    proj_kernel<<<cdiv_host(NSP, 32), TB, 0, stream>>>(xs, NSP, 64, pg1_W,
        pg1_as, pg1_ad, alS, alD, (unsigned short*)HS);
  }
  gat4_fused<true><<<cdiv_host(NSP, 4), TB, 0, stream>>>(
      NSP, pp_ptr, pp_src, pp_cea, alS, alD, dotes + 16, pp_lea,
      (const unsigned short*)HS, pg1_b, sts);   // sts := x2

  // ---- final linear fused with split/softplus ----
  {
    PJob j0{}; j0.xs.p[0] = sts; j0.xs.w[0] = 64; j0.xs.n = 1;
    j0.M = NSP; j0.K = 64; j0.W = fc_W; j0.bias = fc_b; j0.mode = 2;
    j0.Y = (float*)d_out; j0.Y2 = (float*)d_out + (long)NSP * 32;
    LeafArgs la{ ss_ptr, ss_cea, ss_lea, pp_ptr, pp_cea, pp_lea };
    int nb0 = cdiv_host(NSP, 32);
    proj64x2l_kernel<<<nb0, TB, 0, stream>>>(j0, j0, nb0, 0, la);
  }
}